// Round 3
// baseline (100.153 us; speedup 1.0000x reference)
//
#include <hip/hip_runtime.h>

#define BATCH   16384
#define NUM_NEG 64
#define NSAMP   65          // 1 target + 64 negatives
#define EMBED   128

// Two batch rows per block (grid = BATCH/2), 256 threads = 4 waves.
// Each 32-lane half covers one 512B w-row with a float4 load, so each wave
// fetches two samples per VMEM instruction. Per wave, ALL 16 row loads
// (8 per batch row) + 16 bias loads + the sample-64 tails are batch-issued
// before any reduction -> ~8KB in flight per wave.
__global__ __launch_bounds__(256)
void skipgram_kernel(const int* __restrict__ target,
                     const int* __restrict__ context,
                     const int* __restrict__ negatives,
                     const float* __restrict__ emb_table,
                     const float* __restrict__ w_table,
                     const float* __restrict__ b_table,
                     float* __restrict__ out)
{
    const int b0   = blockIdx.x * 2;
    const int b1   = b0 + 1;
    const int tid  = threadIdx.x;
    const int wave = tid >> 6;          // 0..3
    const int half = (tid >> 5) & 1;    // 0: lanes 0-31, 1: lanes 32-63
    const int l32  = tid & 31;
    const int lane = tid & 63;

    __shared__ int   s_idx[2][NSAMP];
    __shared__ float s_logit[2][NSAMP];

    // Stage the sample indices for both batch rows (parallel, coalesced).
    if (tid < NSAMP) {
        s_idx[0][tid] = (tid == 0) ? target[b0]
                                   : negatives[b0 * NUM_NEG + (tid - 1)];
    } else if (tid >= 128 && tid < 128 + NSAMP) {
        const int t = tid - 128;
        s_idx[1][t] = (t == 0) ? target[b1]
                               : negatives[b1 * NUM_NEG + (t - 1)];
    }

    // Context-embedding fragments (independent of s_idx -> issue before sync).
    const float4 eA = *reinterpret_cast<const float4*>(
        &emb_table[(size_t)context[b0] * EMBED + 4 * l32]);
    const float4 eB = *reinterpret_cast<const float4*>(
        &emb_table[(size_t)context[b1] * EMBED + 4 * l32]);

    __syncthreads();

    // Batch-issue all row + bias loads for both batch rows.
    float4 wA[8], wB[8];
    float  bA[8], bB[8];
    #pragma unroll
    for (int i = 0; i < 8; ++i) {
        const int s  = 8 * i + 2 * wave + half;
        const int ia = s_idx[0][s];
        wA[i] = *reinterpret_cast<const float4*>(
                    &w_table[(size_t)ia * EMBED + 4 * l32]);
        bA[i] = b_table[ia];
    }
    #pragma unroll
    for (int i = 0; i < 8; ++i) {
        const int s  = 8 * i + 2 * wave + half;
        const int ib = s_idx[1][s];
        wB[i] = *reinterpret_cast<const float4*>(
                    &w_table[(size_t)ib * EMBED + 4 * l32]);
        bB[i] = b_table[ib];
    }

    // Sample-64 tails: wave 1 half 0 -> row 0; wave 3 half 0 -> row 1.
    // Issued upfront with everything else (not serially after the reduce).
    float4 wT = make_float4(0.f, 0.f, 0.f, 0.f);
    float  bT = 0.f;
    const int  tr      = (wave == 3) ? 1 : 0;
    const bool hasTail = (wave == 1 || wave == 3) && half == 0;
    if (hasTail) {
        const int it = s_idx[tr][64];
        wT = *reinterpret_cast<const float4*>(
                 &w_table[(size_t)it * EMBED + 4 * l32]);
        bT = b_table[it];
    }

    // Reduce row 0 then row 1 (consumes loads in issue order -> staged vmcnt).
    #pragma unroll
    for (int i = 0; i < 8; ++i) {
        const int s = 8 * i + 2 * wave + half;
        float p = eA.x * wA[i].x + eA.y * wA[i].y
                + eA.z * wA[i].z + eA.w * wA[i].w;
        #pragma unroll
        for (int off = 16; off; off >>= 1)
            p += __shfl_xor(p, off, 32);
        if (l32 == 0)
            s_logit[0][s] = p + bA[i];
    }
    #pragma unroll
    for (int i = 0; i < 8; ++i) {
        const int s = 8 * i + 2 * wave + half;
        float p = eB.x * wB[i].x + eB.y * wB[i].y
                + eB.z * wB[i].z + eB.w * wB[i].w;
        #pragma unroll
        for (int off = 16; off; off >>= 1)
            p += __shfl_xor(p, off, 32);
        if (l32 == 0)
            s_logit[1][s] = p + bB[i];
    }
    if (hasTail) {
        const float4 e = tr ? eB : eA;
        float p = e.x * wT.x + e.y * wT.y + e.z * wT.z + e.w * wT.w;
        #pragma unroll
        for (int off = 16; off; off >>= 1)
            p += __shfl_xor(p, off, 32);
        if (l32 == 0)
            s_logit[tr][64] = p + bT;
    }
    __syncthreads();

    // Softmax: wave 0 -> row 0, wave 2 -> row 1. Lane l owns logit l;
    // lane 0 also owns logit 64.
    if ((wave & 1) == 0) {
        const int r  = wave >> 1;
        const int bb = r ? b1 : b0;
        const float x  = s_logit[r][lane];
        const float x2 = (lane == 0) ? s_logit[r][64] : -INFINITY;

        float m = fmaxf(x, x2);
        #pragma unroll
        for (int off = 32; off; off >>= 1)
            m = fmaxf(m, __shfl_xor(m, off, 64));

        const float p  = __expf(x - m);
        const float p2 = (lane == 0) ? __expf(x2 - m) : 0.0f;

        float sum = p + p2;
        #pragma unroll
        for (int off = 32; off; off >>= 1)
            sum += __shfl_xor(sum, off, 64);

        const float inv = 1.0f / sum;
        out[(size_t)bb * NSAMP + lane] = p * inv;
        if (lane == 0)
            out[(size_t)bb * NSAMP + 64] = p2 * inv;
    }
}

extern "C" void kernel_launch(void* const* d_in, const int* in_sizes, int n_in,
                              void* d_out, int out_size, void* d_ws, size_t ws_size,
                              hipStream_t stream)
{
    const int*   target    = (const int*)  d_in[0];
    const int*   context   = (const int*)  d_in[1];
    const int*   negatives = (const int*)  d_in[2];
    const float* emb_table = (const float*)d_in[3];
    const float* w_table   = (const float*)d_in[4];
    const float* b_table   = (const float*)d_in[5];
    float*       out       = (float*)      d_out;

    skipgram_kernel<<<BATCH / 2, 256, 0, stream>>>(
        target, context, negatives, emb_table, w_table, b_table, out);
}